// Round 1
// baseline (3184.701 us; speedup 1.0000x reference)
//
#include <hip/hip_runtime.h>
#include <hip/hip_bf16.h>

#define D_DIM 128
#define N_REL 4

static inline int cdiv(int a, int b) { return (a + b - 1) / b; }

// ---------------------------------------------------------------------------
// cnt[dst*4+rel] += 1 per edge (fp32 counts; exact below 2^24)
// ---------------------------------------------------------------------------
__global__ void count_edges_kernel(const int* __restrict__ dst,
                                   const int* __restrict__ et,
                                   float* __restrict__ cnt, int nEdges) {
    int e = blockIdx.x * blockDim.x + threadIdx.x;
    if (e < nEdges) {
        unsafeAtomicAdd(&cnt[dst[e] * N_REL + et[e]], 1.0f);
    }
}

// norm = 1/max(cnt,1)
__global__ void norm_kernel(const float* __restrict__ cnt,
                            float* __restrict__ normv, int n) {
    int i = blockIdx.x * blockDim.x + threadIdx.x;
    if (i < n) normv[i] = 1.0f / fmaxf(cnt[i], 1.0f);
}

// gcnt[g] = #nodes with batch==g (batch is sorted -> binary search, no atomics)
__global__ void graph_bounds_kernel(const int* __restrict__ batch, int n,
                                    float* __restrict__ gcnt) {
    int g = threadIdx.x;  // 128 graphs
    auto lb = [&](int val) {
        int lo = 0, hi = n;
        while (lo < hi) {
            int mid = (lo + hi) >> 1;
            if (batch[mid] < val) lo = mid + 1; else hi = mid;
        }
        return lo;
    };
    gcnt[g] = (float)(lb(g + 1) - lb(g));
}

// ---------------------------------------------------------------------------
// S[(dst*4+et), :] += x[src, :]   (one thread = 4 dims of one edge)
// ---------------------------------------------------------------------------
__global__ __launch_bounds__(256) void scatter_kernel(
    const float* __restrict__ x, const int* __restrict__ src,
    const int* __restrict__ dst, const int* __restrict__ et,
    float* __restrict__ S, int nEdges) {
    int gid = blockIdx.x * blockDim.x + threadIdx.x;
    int e = gid >> 5;
    if (e >= nEdges) return;
    int q = (gid & 31) * 4;
    const float4 v = *(const float4*)(x + (size_t)src[e] * D_DIM + q);
    float* p = S + ((size_t)dst[e] * N_REL + et[e]) * D_DIM + q;
    unsafeAtomicAdd(p + 0, v.x);
    unsafeAtomicAdd(p + 1, v.y);
    unsafeAtomicAdd(p + 2, v.z);
    unsafeAtomicAdd(p + 3, v.w);
}

// ---------------------------------------------------------------------------
// out[n,f] = relu( sum_k A[n,k]*B[k,f] + bias[f] )
//   A[n,k] = k<512 ? S[n,k]*norm[n*4 + k/128] : X[n,k-512]   (K = 640)
//   B[k,f] = k<512 ? Wrel[k*128+f]            : Wroot[(k-512)*128+f]
// Tiled fp32 GEMM: BM=64, BN=128, BK=16, 256 threads, 4x8 per-thread tile.
// ---------------------------------------------------------------------------
__global__ __launch_bounds__(256) void transform_kernel(
    const float* __restrict__ S, const float* __restrict__ normv,
    const float* __restrict__ X, const float* __restrict__ Wrel,
    const float* __restrict__ Wroot, const float* __restrict__ bias,
    float* __restrict__ out, int n_nodes) {
    __shared__ float As[64][17];   // +1 pad breaks bank-conflict strides
    __shared__ float Bs[16][128];

    const int tid = threadIdx.x;
    const int row0 = blockIdx.x * 64;
    const int tr = tid >> 4;        // 0..15 -> rows tr*4 .. tr*4+3
    const int tc = tid & 15;        // 0..15 -> cols tc*8 .. tc*8+7

    const int lm = tid >> 2;        // A-load row 0..63
    const int lk = (tid & 3) * 4;   // A-load k-offset {0,4,8,12}
    const int bk = tid >> 4;        // B-load row 0..15
    const int bf = (tid & 15) * 8;  // B-load col 0..120

    float acc[4][8];
#pragma unroll
    for (int i = 0; i < 4; i++)
#pragma unroll
        for (int j = 0; j < 8; j++) acc[i][j] = 0.0f;

    for (int k0 = 0; k0 < 512 + D_DIM; k0 += 16) {
        // ---- A tile (64 x 16) ----
        {
            int n = row0 + lm;
            float4 v = make_float4(0.f, 0.f, 0.f, 0.f);
            if (n < n_nodes) {
                if (k0 < 512) {
                    float sc = normv[n * N_REL + (k0 >> 7)];
                    float4 s4 = *(const float4*)(S + (size_t)n * 512 + k0 + lk);
                    v = make_float4(s4.x * sc, s4.y * sc, s4.z * sc, s4.w * sc);
                } else {
                    v = *(const float4*)(X + (size_t)n * D_DIM + (k0 - 512) + lk);
                }
            }
            As[lm][lk + 0] = v.x;
            As[lm][lk + 1] = v.y;
            As[lm][lk + 2] = v.z;
            As[lm][lk + 3] = v.w;
        }
        // ---- B tile (16 x 128) ----
        {
            const float* Wsrc = (k0 < 512) ? (Wrel + (size_t)k0 * D_DIM)
                                           : (Wroot + (size_t)(k0 - 512) * D_DIM);
            float4 v0 = *(const float4*)(Wsrc + bk * D_DIM + bf);
            float4 v1 = *(const float4*)(Wsrc + bk * D_DIM + bf + 4);
            *(float4*)&Bs[bk][bf] = v0;
            *(float4*)&Bs[bk][bf + 4] = v1;
        }
        __syncthreads();
#pragma unroll
        for (int kk = 0; kk < 16; ++kk) {
            float a[4];
#pragma unroll
            for (int i = 0; i < 4; i++) a[i] = As[tr * 4 + i][kk];
            float4 b0 = *(const float4*)&Bs[kk][tc * 8];
            float4 b1 = *(const float4*)&Bs[kk][tc * 8 + 4];
            float b[8] = {b0.x, b0.y, b0.z, b0.w, b1.x, b1.y, b1.z, b1.w};
#pragma unroll
            for (int i = 0; i < 4; i++)
#pragma unroll
                for (int j = 0; j < 8; j++)
                    acc[i][j] = fmaf(a[i], b[j], acc[i][j]);
        }
        __syncthreads();
    }

    // ---- epilogue: +bias, relu, store ----
#pragma unroll
    for (int i = 0; i < 4; i++) {
        int n = row0 + tr * 4 + i;
        if (n >= n_nodes) continue;
        int f = tc * 8;
        float4 o0, o1;
        o0.x = fmaxf(acc[i][0] + bias[f + 0], 0.f);
        o0.y = fmaxf(acc[i][1] + bias[f + 1], 0.f);
        o0.z = fmaxf(acc[i][2] + bias[f + 2], 0.f);
        o0.w = fmaxf(acc[i][3] + bias[f + 3], 0.f);
        o1.x = fmaxf(acc[i][4] + bias[f + 4], 0.f);
        o1.y = fmaxf(acc[i][5] + bias[f + 5], 0.f);
        o1.z = fmaxf(acc[i][6] + bias[f + 6], 0.f);
        o1.w = fmaxf(acc[i][7] + bias[f + 7], 0.f);
        *(float4*)(out + (size_t)n * D_DIM + f) = o0;
        *(float4*)(out + (size_t)n * D_DIM + f + 4) = o1;
    }
}

// ---------------------------------------------------------------------------
// gsum[g, d] += h[n, d] for batch[n]==g, run-length flush over sorted batch
// ---------------------------------------------------------------------------
__global__ __launch_bounds__(128) void pool_kernel(
    const float* __restrict__ h, const int* __restrict__ batch,
    float* __restrict__ gsum, int n_nodes) {
    int d = threadIdx.x;  // 128
    int n0 = blockIdx.x * 64;
    if (n0 >= n_nodes) return;
    int n1 = min(n0 + 64, n_nodes);
    int gcur = batch[n0];
    float acc = 0.0f;
    for (int n = n0; n < n1; ++n) {
        int g = batch[n];
        float v = h[(size_t)n * D_DIM + d];
        if (g != gcur) {
            unsafeAtomicAdd(&gsum[gcur * D_DIM + d], acc);
            acc = 0.0f;
            gcur = g;
        }
        acc += v;
    }
    unsafeAtomicAdd(&gsum[gcur * D_DIM + d], acc);
}

// out[g,c] = (gsum[g,:]/max(gcnt,1)) @ Wcls[:,c] + bcls[c]
__global__ void cls_kernel(const float* __restrict__ gsum,
                           const float* __restrict__ gcnt,
                           const float* __restrict__ Wcls,
                           const float* __restrict__ bcls,
                           float* __restrict__ out) {
    int id = blockIdx.x * blockDim.x + threadIdx.x;
    if (id >= 128 * 16) return;
    int g = id >> 4, c = id & 15;
    float rc = 1.0f / fmaxf(gcnt[g], 1.0f);
    float acc = 0.0f;
    for (int d = 0; d < D_DIM; ++d)
        acc = fmaf(gsum[g * D_DIM + d], Wcls[d * 16 + c], acc);
    out[id] = acc * rc + bcls[c];
}

extern "C" void kernel_launch(void* const* d_in, const int* in_sizes, int n_in,
                              void* d_out, int out_size, void* d_ws, size_t ws_size,
                              hipStream_t stream) {
    const float* x      = (const float*)d_in[0];
    const int*   ei     = (const int*)d_in[1];
    const int*   etype  = (const int*)d_in[2];
    const int*   batch  = (const int*)d_in[3];
    const float* Wrel1  = (const float*)d_in[4];
    const float* Wroot1 = (const float*)d_in[5];
    const float* b1     = (const float*)d_in[6];
    const float* Wrel2  = (const float*)d_in[7];
    const float* Wroot2 = (const float*)d_in[8];
    const float* b2     = (const float*)d_in[9];
    const float* Wcls   = (const float*)d_in[10];
    const float* bcls   = (const float*)d_in[11];
    float* out = (float*)d_out;

    const int N = in_sizes[0] / D_DIM;       // 50000
    const int E = in_sizes[1] / 2;           // 800000
    const int* src = ei;
    const int* dst = ei + E;

    // workspace layout (floats)
    float* S     = (float*)d_ws;                     // N*4*128 = 25.6M
    float* h1    = S + (size_t)N * N_REL * D_DIM;    // 6.4M
    float* h2    = h1 + (size_t)N * D_DIM;           // 6.4M
    float* cnt   = h2 + (size_t)N * D_DIM;           // 200k
    float* normv = cnt + (size_t)N * N_REL;          // 200k
    float* gsum  = normv + (size_t)N * N_REL;        // 16384
    float* gcnt  = gsum + 128 * D_DIM;               // 128

    const size_t S_bytes = (size_t)N * N_REL * D_DIM * sizeof(float);

    // zero accumulators (ws is poisoned 0xAA before every timed call)
    hipMemsetAsync(cnt, 0, (size_t)N * N_REL * sizeof(float), stream);
    hipMemsetAsync(S, 0, S_bytes, stream);
    hipMemsetAsync(gsum, 0, 128 * D_DIM * sizeof(float), stream);

    // degree counts + norms + graph sizes (edge structure shared by both layers)
    count_edges_kernel<<<cdiv(E, 256), 256, 0, stream>>>(dst, etype, cnt, E);
    graph_bounds_kernel<<<1, 128, 0, stream>>>(batch, N, gcnt);
    norm_kernel<<<cdiv(N * N_REL, 256), 256, 0, stream>>>(cnt, normv, N * N_REL);

    // ---- layer 1 ----
    scatter_kernel<<<cdiv(E * 32, 256), 256, 0, stream>>>(x, src, dst, etype, S, E);
    transform_kernel<<<cdiv(N, 64), 256, 0, stream>>>(S, normv, x, Wrel1, Wroot1,
                                                      b1, h1, N);

    // ---- layer 2 ----
    hipMemsetAsync(S, 0, S_bytes, stream);
    scatter_kernel<<<cdiv(E * 32, 256), 256, 0, stream>>>(h1, src, dst, etype, S, E);
    transform_kernel<<<cdiv(N, 64), 256, 0, stream>>>(S, normv, h1, Wrel2, Wroot2,
                                                      b2, h2, N);

    // ---- global mean pool + classifier ----
    pool_kernel<<<cdiv(N, 64), 128, 0, stream>>>(h2, batch, gsum, N);
    cls_kernel<<<8, 256, 0, stream>>>(gsum, gcnt, Wcls, bcls, out);
}

// Round 2
// 753.555 us; speedup vs baseline: 4.2262x; 4.2262x over previous
//
#include <hip/hip_runtime.h>
#include <hip/hip_bf16.h>

#define D_DIM 128
#define N_REL 4

static inline int cdiv(int a, int b) { return (a + b - 1) / b; }

// ---------------------------------------------------------------------------
// icnt[dst*4+rel]++ per edge (int atomics, low contention: avg 4/segment)
// ---------------------------------------------------------------------------
__global__ void count_edges_kernel(const int* __restrict__ dst,
                                   const int* __restrict__ et,
                                   int* __restrict__ icnt, int nEdges) {
    int e = blockIdx.x * blockDim.x + threadIdx.x;
    if (e < nEdges) atomicAdd(&icnt[dst[e] * N_REL + et[e]], 1);
}

// ---------------------------------------------------------------------------
// 3-kernel exclusive scan over nseg=200000 ints
// ---------------------------------------------------------------------------
__global__ void scan_block_sums(const int* __restrict__ icnt,
                                int* __restrict__ bsum, int nseg) {
    __shared__ int s[256];
    int t = threadIdx.x;
    int i = blockIdx.x * 256 + t;
    s[t] = (i < nseg) ? icnt[i] : 0;
    __syncthreads();
    for (int off = 128; off > 0; off >>= 1) {
        if (t < off) s[t] += s[t + off];
        __syncthreads();
    }
    if (t == 0) bsum[blockIdx.x] = s[0];
}

__global__ void scan_partials(int* __restrict__ bsum, int nb) {
    __shared__ int s[1024];
    int t = threadIdx.x;
    int v = (t < nb) ? bsum[t] : 0;
    s[t] = v;
    __syncthreads();
    for (int off = 1; off < 1024; off <<= 1) {
        int u = (t >= off) ? s[t - off] : 0;
        __syncthreads();
        s[t] += u;
        __syncthreads();
    }
    if (t < nb) bsum[t] = s[t] - v;  // exclusive prefix of block sums
}

__global__ void scan_final(const int* __restrict__ icnt,
                           const int* __restrict__ bsum,
                           int* __restrict__ offsets, int* __restrict__ wpos,
                           int nseg) {
    __shared__ int s[256];
    int t = threadIdx.x;
    int i = blockIdx.x * 256 + t;
    int v = (i < nseg) ? icnt[i] : 0;
    s[t] = v;
    __syncthreads();
    for (int off = 1; off < 256; off <<= 1) {
        int u = (t >= off) ? s[t - off] : 0;
        __syncthreads();
        s[t] += u;
        __syncthreads();
    }
    int excl = s[t] - v + bsum[blockIdx.x];
    if (i < nseg) {
        offsets[i] = excl;
        wpos[i] = excl;
        if (i == nseg - 1) offsets[nseg] = excl + v;
    }
}

// esorted[offsets[seg] + k] = src of k-th edge of segment (order irrelevant)
__global__ void place_edges_kernel(const int* __restrict__ src,
                                   const int* __restrict__ dst,
                                   const int* __restrict__ et,
                                   int* __restrict__ wpos,
                                   int* __restrict__ esorted, int nEdges) {
    int e = blockIdx.x * blockDim.x + threadIdx.x;
    if (e < nEdges) {
        int seg = dst[e] * N_REL + et[e];
        int pos = atomicAdd(&wpos[seg], 1);
        esorted[pos] = src[e];
    }
}

// gcnt[g] = #nodes with batch==g (batch sorted -> binary search)
__global__ void graph_bounds_kernel(const int* __restrict__ batch, int n,
                                    float* __restrict__ gcnt) {
    int g = threadIdx.x;  // 128 graphs
    auto lb = [&](int val) {
        int lo = 0, hi = n;
        while (lo < hi) {
            int mid = (lo + hi) >> 1;
            if (batch[mid] < val) lo = mid + 1; else hi = mid;
        }
        return lo;
    };
    gcnt[g] = (float)(lb(g + 1) - lb(g));
}

// ---------------------------------------------------------------------------
// Fused RGCN layer: out[n,f] = relu( sum_r mean_{e in seg(n,r)} X[src_e] @ Wrel[r]
//                                    + X[n] @ Wroot + bias )
// Block = 256 threads = 4 waves, 64 nodes (rows) x 128 cols.
// 5 phases: r=0..3 (gather+mean into LDS A-tile, GEMM vs Wrel[r]) + root phase.
// ---------------------------------------------------------------------------
__global__ __launch_bounds__(256) void rgcn_fused_kernel(
    const float* __restrict__ X, const int* __restrict__ offsets,
    const int* __restrict__ esorted, const float* __restrict__ Wrel,
    const float* __restrict__ Wroot, const float* __restrict__ bias,
    float* __restrict__ out, int n_nodes) {
    __shared__ float As[64][129];  // +1 pad: compute reads stride-129 rows
    __shared__ float Bs[16][128];

    const int tid = threadIdx.x;
    const int wave = tid >> 6;      // 0..3
    const int lane = tid & 63;
    const int half = lane >> 5;     // 0/1: which node of the pair
    const int hl = lane & 31;       // handles floats [hl*4, hl*4+4)
    const int row0 = blockIdx.x * 64;

    const int tr = tid >> 4;        // compute: rows tr*4..tr*4+3
    const int tc = tid & 15;        // compute: cols tc*8..tc*8+7
    const int bk = tid >> 4;        // B-load row
    const int bf = (tid & 15) * 8;  // B-load col

    float acc[4][8];
#pragma unroll
    for (int i = 0; i < 4; i++)
#pragma unroll
        for (int j = 0; j < 8; j++) acc[i][j] = 0.0f;

    for (int phase = 0; phase < 5; ++phase) {
        // ---- fill As[64][128] ----
        if (phase < N_REL) {
            // each half-wave aggregates one node's segment; 2 nodes/iter/wave
#pragma unroll 1
            for (int i = 0; i < 16; i += 2) {
                int row = wave * 16 + i + half;
                int n = row0 + row;
                float4 v0 = make_float4(0.f, 0.f, 0.f, 0.f);
                float4 v1 = make_float4(0.f, 0.f, 0.f, 0.f);
                if (n < n_nodes) {
                    int seg = n * N_REL + phase;
                    int beg = offsets[seg];
                    int end = offsets[seg + 1];
                    int e = beg;
                    for (; e + 1 < end; e += 2) {
                        int s0 = esorted[e];
                        int s1 = esorted[e + 1];
                        float4 x0 = *(const float4*)(X + (size_t)s0 * D_DIM + hl * 4);
                        float4 x1 = *(const float4*)(X + (size_t)s1 * D_DIM + hl * 4);
                        v0.x += x0.x; v0.y += x0.y; v0.z += x0.z; v0.w += x0.w;
                        v1.x += x1.x; v1.y += x1.y; v1.z += x1.z; v1.w += x1.w;
                    }
                    if (e < end) {
                        int s0 = esorted[e];
                        float4 x0 = *(const float4*)(X + (size_t)s0 * D_DIM + hl * 4);
                        v0.x += x0.x; v0.y += x0.y; v0.z += x0.z; v0.w += x0.w;
                    }
                    float sc = 1.0f / fmaxf((float)(end - beg), 1.0f);
                    v0.x = (v0.x + v1.x) * sc;
                    v0.y = (v0.y + v1.y) * sc;
                    v0.z = (v0.z + v1.z) * sc;
                    v0.w = (v0.w + v1.w) * sc;
                }
                As[row][hl * 4 + 0] = v0.x;
                As[row][hl * 4 + 1] = v0.y;
                As[row][hl * 4 + 2] = v0.z;
                As[row][hl * 4 + 3] = v0.w;
            }
        } else {
            // root phase: copy X rows
#pragma unroll 1
            for (int i = 0; i < 16; i += 2) {
                int row = wave * 16 + i + half;
                int n = row0 + row;
                float4 v = make_float4(0.f, 0.f, 0.f, 0.f);
                if (n < n_nodes) v = *(const float4*)(X + (size_t)n * D_DIM + hl * 4);
                As[row][hl * 4 + 0] = v.x;
                As[row][hl * 4 + 1] = v.y;
                As[row][hl * 4 + 2] = v.z;
                As[row][hl * 4 + 3] = v.w;
            }
        }
        __syncthreads();

        const float* W = (phase < N_REL) ? (Wrel + (size_t)phase * D_DIM * D_DIM)
                                         : Wroot;
        for (int k0 = 0; k0 < D_DIM; k0 += 16) {
            const float* wrow = W + (size_t)(k0 + bk) * D_DIM + bf;
            float4 w0 = *(const float4*)(wrow);
            float4 w1 = *(const float4*)(wrow + 4);
            *(float4*)&Bs[bk][bf] = w0;
            *(float4*)&Bs[bk][bf + 4] = w1;
            __syncthreads();
#pragma unroll
            for (int kk = 0; kk < 16; ++kk) {
                float a[4];
#pragma unroll
                for (int i = 0; i < 4; i++) a[i] = As[tr * 4 + i][k0 + kk];
                float4 b0 = *(const float4*)&Bs[kk][tc * 8];
                float4 b1 = *(const float4*)&Bs[kk][tc * 8 + 4];
                float b[8] = {b0.x, b0.y, b0.z, b0.w, b1.x, b1.y, b1.z, b1.w};
#pragma unroll
                for (int i = 0; i < 4; i++)
#pragma unroll
                    for (int j = 0; j < 8; j++)
                        acc[i][j] = fmaf(a[i], b[j], acc[i][j]);
            }
            __syncthreads();  // also guards As before next phase's fill
        }
    }

    // ---- epilogue: +bias, relu, store ----
#pragma unroll
    for (int i = 0; i < 4; i++) {
        int n = row0 + tr * 4 + i;
        if (n >= n_nodes) continue;
        int f = tc * 8;
        float4 o0, o1;
        o0.x = fmaxf(acc[i][0] + bias[f + 0], 0.f);
        o0.y = fmaxf(acc[i][1] + bias[f + 1], 0.f);
        o0.z = fmaxf(acc[i][2] + bias[f + 2], 0.f);
        o0.w = fmaxf(acc[i][3] + bias[f + 3], 0.f);
        o1.x = fmaxf(acc[i][4] + bias[f + 4], 0.f);
        o1.y = fmaxf(acc[i][5] + bias[f + 5], 0.f);
        o1.z = fmaxf(acc[i][6] + bias[f + 6], 0.f);
        o1.w = fmaxf(acc[i][7] + bias[f + 7], 0.f);
        *(float4*)(out + (size_t)n * D_DIM + f) = o0;
        *(float4*)(out + (size_t)n * D_DIM + f + 4) = o1;
    }
}

// ---------------------------------------------------------------------------
// gsum[g, d] += h[n, d], run-length flush over sorted batch
// ---------------------------------------------------------------------------
__global__ __launch_bounds__(128) void pool_kernel(
    const float* __restrict__ h, const int* __restrict__ batch,
    float* __restrict__ gsum, int n_nodes) {
    int d = threadIdx.x;  // 128
    int n0 = blockIdx.x * 64;
    if (n0 >= n_nodes) return;
    int n1 = min(n0 + 64, n_nodes);
    int gcur = batch[n0];
    float acc = 0.0f;
    for (int n = n0; n < n1; ++n) {
        int g = batch[n];
        float v = h[(size_t)n * D_DIM + d];
        if (g != gcur) {
            unsafeAtomicAdd(&gsum[gcur * D_DIM + d], acc);
            acc = 0.0f;
            gcur = g;
        }
        acc += v;
    }
    unsafeAtomicAdd(&gsum[gcur * D_DIM + d], acc);
}

__global__ void cls_kernel(const float* __restrict__ gsum,
                           const float* __restrict__ gcnt,
                           const float* __restrict__ Wcls,
                           const float* __restrict__ bcls,
                           float* __restrict__ out) {
    int id = blockIdx.x * blockDim.x + threadIdx.x;
    if (id >= 128 * 16) return;
    int g = id >> 4, c = id & 15;
    float rc = 1.0f / fmaxf(gcnt[g], 1.0f);
    float acc = 0.0f;
    for (int d = 0; d < D_DIM; ++d)
        acc = fmaf(gsum[g * D_DIM + d], Wcls[d * 16 + c], acc);
    out[id] = acc * rc + bcls[c];
}

extern "C" void kernel_launch(void* const* d_in, const int* in_sizes, int n_in,
                              void* d_out, int out_size, void* d_ws, size_t ws_size,
                              hipStream_t stream) {
    const float* x      = (const float*)d_in[0];
    const int*   ei     = (const int*)d_in[1];
    const int*   etype  = (const int*)d_in[2];
    const int*   batch  = (const int*)d_in[3];
    const float* Wrel1  = (const float*)d_in[4];
    const float* Wroot1 = (const float*)d_in[5];
    const float* b1     = (const float*)d_in[6];
    const float* Wrel2  = (const float*)d_in[7];
    const float* Wroot2 = (const float*)d_in[8];
    const float* b2     = (const float*)d_in[9];
    const float* Wcls   = (const float*)d_in[10];
    const float* bcls   = (const float*)d_in[11];
    float* out = (float*)d_out;

    const int N = in_sizes[0] / D_DIM;  // 50000
    const int E = in_sizes[1] / 2;      // 800000
    const int NSEG = N * N_REL;         // 200000
    const int* src = ei;
    const int* dst = ei + E;

    // workspace layout
    float* h1    = (float*)d_ws;                   // N*128
    float* h2    = h1 + (size_t)N * D_DIM;         // N*128
    float* gsum  = h2 + (size_t)N * D_DIM;         // 128*128
    float* gcnt  = gsum + 128 * D_DIM;             // 128
    int* icnt    = (int*)(gcnt + 128);             // NSEG
    int* offsets = icnt + NSEG;                    // NSEG+1
    int* wpos    = offsets + NSEG + 1;             // NSEG
    int* bsum    = wpos + NSEG;                    // 1024
    int* esorted = bsum + 1024;                    // E

    const int nb = cdiv(NSEG, 256);  // 782 scan blocks (<=1024)

    hipMemsetAsync(icnt, 0, (size_t)NSEG * sizeof(int), stream);
    hipMemsetAsync(gsum, 0, 128 * D_DIM * sizeof(float), stream);

    // ---- CSR build over seg = dst*4 + rel ----
    count_edges_kernel<<<cdiv(E, 256), 256, 0, stream>>>(dst, etype, icnt, E);
    scan_block_sums<<<nb, 256, 0, stream>>>(icnt, bsum, NSEG);
    scan_partials<<<1, 1024, 0, stream>>>(bsum, nb);
    scan_final<<<nb, 256, 0, stream>>>(icnt, bsum, offsets, wpos, NSEG);
    place_edges_kernel<<<cdiv(E, 256), 256, 0, stream>>>(src, dst, etype, wpos,
                                                         esorted, E);
    graph_bounds_kernel<<<1, 128, 0, stream>>>(batch, N, gcnt);

    // ---- fused layers ----
    rgcn_fused_kernel<<<cdiv(N, 64), 256, 0, stream>>>(
        x, offsets, esorted, Wrel1, Wroot1, b1, h1, N);
    rgcn_fused_kernel<<<cdiv(N, 64), 256, 0, stream>>>(
        h1, offsets, esorted, Wrel2, Wroot2, b2, h2, N);

    // ---- global mean pool + classifier ----
    pool_kernel<<<cdiv(N, 64), 128, 0, stream>>>(h2, batch, gsum, N);
    cls_kernel<<<8, 256, 0, stream>>>(gsum, gcnt, Wcls, bcls, out);
}

// Round 3
// 434.586 us; speedup vs baseline: 7.3281x; 1.7340x over previous
//
#include <hip/hip_runtime.h>

#define D_DIM 128
#define N_REL 4
#define AS_STRIDE 136  // bf16 elems per A-tile row (128 + 8 pad)

typedef __attribute__((ext_vector_type(8))) short bf16x8;
typedef __attribute__((ext_vector_type(4))) float f32x4;

static inline int cdiv(int a, int b) { return (a + b - 1) / b; }

__device__ inline ushort f2bf(float f) {
    union { float f; unsigned u; } v;
    v.f = f;
    unsigned r = v.u + 0x7FFFu + ((v.u >> 16) & 1u);  // RNE
    return (ushort)(r >> 16);
}

// ---------------------------------------------------------------------------
// icnt[dst*4+rel]++ per edge
// ---------------------------------------------------------------------------
__global__ void count_edges_kernel(const int* __restrict__ dst,
                                   const int* __restrict__ et,
                                   int* __restrict__ icnt, int nEdges) {
    int e = blockIdx.x * blockDim.x + threadIdx.x;
    if (e < nEdges) atomicAdd(&icnt[dst[e] * N_REL + et[e]], 1);
}

// ---------------------------------------------------------------------------
// 3-kernel exclusive scan over nseg=200000 ints
// ---------------------------------------------------------------------------
__global__ void scan_block_sums(const int* __restrict__ icnt,
                                int* __restrict__ bsum, int nseg) {
    __shared__ int s[256];
    int t = threadIdx.x;
    int i = blockIdx.x * 256 + t;
    s[t] = (i < nseg) ? icnt[i] : 0;
    __syncthreads();
    for (int off = 128; off > 0; off >>= 1) {
        if (t < off) s[t] += s[t + off];
        __syncthreads();
    }
    if (t == 0) bsum[blockIdx.x] = s[0];
}

__global__ void scan_partials(int* __restrict__ bsum, int nb) {
    __shared__ int s[1024];
    int t = threadIdx.x;
    int v = (t < nb) ? bsum[t] : 0;
    s[t] = v;
    __syncthreads();
    for (int off = 1; off < 1024; off <<= 1) {
        int u = (t >= off) ? s[t - off] : 0;
        __syncthreads();
        s[t] += u;
        __syncthreads();
    }
    if (t < nb) bsum[t] = s[t] - v;  // exclusive prefix of block sums
}

__global__ void scan_final(const int* __restrict__ icnt,
                           const int* __restrict__ bsum,
                           int* __restrict__ offsets, int* __restrict__ wpos,
                           int nseg) {
    __shared__ int s[256];
    int t = threadIdx.x;
    int i = blockIdx.x * 256 + t;
    int v = (i < nseg) ? icnt[i] : 0;
    s[t] = v;
    __syncthreads();
    for (int off = 1; off < 256; off <<= 1) {
        int u = (t >= off) ? s[t - off] : 0;
        __syncthreads();
        s[t] += u;
        __syncthreads();
    }
    int excl = s[t] - v + bsum[blockIdx.x];
    if (i < nseg) {
        offsets[i] = excl;
        wpos[i] = excl;
        if (i == nseg - 1) offsets[nseg] = excl + v;
    }
}

__global__ void place_edges_kernel(const int* __restrict__ src,
                                   const int* __restrict__ dst,
                                   const int* __restrict__ et,
                                   int* __restrict__ wpos,
                                   int* __restrict__ esorted, int nEdges) {
    int e = blockIdx.x * blockDim.x + threadIdx.x;
    if (e < nEdges) {
        int seg = dst[e] * N_REL + et[e];
        int pos = atomicAdd(&wpos[seg], 1);
        esorted[pos] = src[e];
    }
}

__global__ void graph_bounds_kernel(const int* __restrict__ batch, int n,
                                    float* __restrict__ gcnt) {
    int g = threadIdx.x;  // 128 graphs
    auto lb = [&](int val) {
        int lo = 0, hi = n;
        while (lo < hi) {
            int mid = (lo + hi) >> 1;
            if (batch[mid] < val) lo = mid + 1; else hi = mid;
        }
        return lo;
    };
    gcnt[g] = (float)(lb(g + 1) - lb(g));
}

// ---------------------------------------------------------------------------
// Pack one layer's weights [Wrel(4) | Wroot] (fp32 row-major [k][n]) into
// bf16 MFMA B-fragment layout for 16x16x32:
//   lane holds B[k = kt*32 + (lane>>4)*8 + j][n = nt*16 + (lane&15)], j=0..7
//   out[((mat*32 + kt*8 + nt)*64 + lane)*8 + j]
// grid: (8 blocks x 5 mats), 256 threads
// ---------------------------------------------------------------------------
__global__ void pack_w_kernel(const float* __restrict__ Wrel,
                              const float* __restrict__ Wroot,
                              ushort* __restrict__ out) {
    int mat = blockIdx.y;
    const float* W = (mat < N_REL) ? (Wrel + (size_t)mat * D_DIM * D_DIM) : Wroot;
    int t = blockIdx.x * 256 + threadIdx.x;  // 0..2047 within mat
    int lane = t & 63;
    int tile = t >> 6;  // 0..31 = kt*8+nt
    int kt = tile >> 3;
    int nt = tile & 7;
    int n = nt * 16 + (lane & 15);
    int kb = kt * 32 + (lane >> 4) * 8;
    ushort* o = out + (((size_t)mat * 32 + tile) * 64 + lane) * 8;
    ushort4 lo, hi;
    lo.x = f2bf(W[(kb + 0) * D_DIM + n]);
    lo.y = f2bf(W[(kb + 1) * D_DIM + n]);
    lo.z = f2bf(W[(kb + 2) * D_DIM + n]);
    lo.w = f2bf(W[(kb + 3) * D_DIM + n]);
    hi.x = f2bf(W[(kb + 4) * D_DIM + n]);
    hi.y = f2bf(W[(kb + 5) * D_DIM + n]);
    hi.z = f2bf(W[(kb + 6) * D_DIM + n]);
    hi.w = f2bf(W[(kb + 7) * D_DIM + n]);
    *(ushort4*)(o) = lo;
    *(ushort4*)(o + 4) = hi;
}

// ---------------------------------------------------------------------------
// Fused RGCN layer with bf16 MFMA.
// Block = 256 threads = 4 waves; 64 nodes x 128 out-cols per block.
// Wave w owns rows [w*16, w*16+16): gathers them into its A-strip (bf16 LDS)
// and runs 16x16x32 MFMA vs pre-packed weights. No __syncthreads needed —
// each wave only touches its own strip (same-wave LDS RAW ordered by lgkmcnt).
// 5 phases: rel 0..3 (gather+mean) + root (copy X).
// ---------------------------------------------------------------------------
__global__ __launch_bounds__(256, 4) void rgcn_fused_kernel(
    const float* __restrict__ X, const int* __restrict__ offsets,
    const int* __restrict__ esorted, const ushort* __restrict__ Wpk,
    const float* __restrict__ bias, float* __restrict__ out, int n_nodes) {
    __shared__ ushort As[64][AS_STRIDE];

    const int tid = threadIdx.x;
    const int wave = tid >> 6;
    const int lane = tid & 63;
    const int half = lane >> 5;  // which row of the pair
    const int hl = lane & 31;    // covers floats [hl*4, hl*4+4)
    const int row0 = blockIdx.x * 64;

    f32x4 acc[8];
#pragma unroll
    for (int nt = 0; nt < 8; ++nt) acc[nt] = (f32x4){0.f, 0.f, 0.f, 0.f};

    const ushort* arow0 = &As[wave * 16 + (lane & 15)][(lane >> 4) * 8];

    for (int phase = 0; phase < 5; ++phase) {
        // ---- gather this wave's 16 rows into its A-strip (bf16) ----
#pragma unroll 1
        for (int i = 0; i < 16; i += 2) {
            int row = wave * 16 + i + half;
            int n = row0 + row;
            float4 v0 = make_float4(0.f, 0.f, 0.f, 0.f);
            float4 v1 = make_float4(0.f, 0.f, 0.f, 0.f);
            float4 v2 = make_float4(0.f, 0.f, 0.f, 0.f);
            float4 v3 = make_float4(0.f, 0.f, 0.f, 0.f);
            float sc = 1.0f;
            if (n < n_nodes) {
                if (phase < N_REL) {
                    int seg = n * N_REL + phase;
                    int beg = offsets[seg];
                    int end = offsets[seg + 1];
                    int e = beg;
                    for (; e + 4 <= end; e += 4) {
                        int s0 = esorted[e + 0];
                        int s1 = esorted[e + 1];
                        int s2 = esorted[e + 2];
                        int s3 = esorted[e + 3];
                        float4 x0 = *(const float4*)(X + (size_t)s0 * D_DIM + hl * 4);
                        float4 x1 = *(const float4*)(X + (size_t)s1 * D_DIM + hl * 4);
                        float4 x2 = *(const float4*)(X + (size_t)s2 * D_DIM + hl * 4);
                        float4 x3 = *(const float4*)(X + (size_t)s3 * D_DIM + hl * 4);
                        v0.x += x0.x; v0.y += x0.y; v0.z += x0.z; v0.w += x0.w;
                        v1.x += x1.x; v1.y += x1.y; v1.z += x1.z; v1.w += x1.w;
                        v2.x += x2.x; v2.y += x2.y; v2.z += x2.z; v2.w += x2.w;
                        v3.x += x3.x; v3.y += x3.y; v3.z += x3.z; v3.w += x3.w;
                    }
                    for (; e < end; ++e) {
                        int s0 = esorted[e];
                        float4 x0 = *(const float4*)(X + (size_t)s0 * D_DIM + hl * 4);
                        v0.x += x0.x; v0.y += x0.y; v0.z += x0.z; v0.w += x0.w;
                    }
                    sc = 1.0f / fmaxf((float)(end - beg), 1.0f);
                } else {
                    v0 = *(const float4*)(X + (size_t)n * D_DIM + hl * 4);
                }
            }
            float4 v;
            v.x = (v0.x + v1.x + v2.x + v3.x) * sc;
            v.y = (v0.y + v1.y + v2.y + v3.y) * sc;
            v.z = (v0.z + v1.z + v2.z + v3.z) * sc;
            v.w = (v0.w + v1.w + v2.w + v3.w) * sc;
            ushort4 o;
            o.x = f2bf(v.x);
            o.y = f2bf(v.y);
            o.z = f2bf(v.z);
            o.w = f2bf(v.w);
            *(ushort4*)&As[row][hl * 4] = o;
        }

        // ---- MFMA: this wave's 16-row strip x 128 cols, K=128 ----
        const ushort* Wp = Wpk + (size_t)phase * 32 * 64 * 8;
#pragma unroll
        for (int kt = 0; kt < 4; ++kt) {
            bf16x8 a = *(const bf16x8*)(arow0 + kt * 32);
#pragma unroll
            for (int nt = 0; nt < 8; ++nt) {
                bf16x8 b = *(const bf16x8*)(Wp + (((size_t)(kt * 8 + nt)) * 64 + lane) * 8);
                acc[nt] = __builtin_amdgcn_mfma_f32_16x16x32_bf16(a, b, acc[nt], 0, 0, 0);
            }
        }
    }

    // ---- epilogue: +bias, relu, store (C/D: col=lane&15, row=quad*4+reg) ----
    const int mcol = lane & 15;
    const int rq = lane >> 4;
#pragma unroll
    for (int nt = 0; nt < 8; ++nt) {
        int col = nt * 16 + mcol;
        float bv = bias[col];
#pragma unroll
        for (int r = 0; r < 4; ++r) {
            int row = row0 + wave * 16 + rq * 4 + r;
            if (row < n_nodes)
                out[(size_t)row * D_DIM + col] = fmaxf(acc[nt][r] + bv, 0.0f);
        }
    }
}

// ---------------------------------------------------------------------------
// gsum[g, d] += h[n, d], run-length flush over sorted batch
// ---------------------------------------------------------------------------
__global__ __launch_bounds__(128) void pool_kernel(
    const float* __restrict__ h, const int* __restrict__ batch,
    float* __restrict__ gsum, int n_nodes) {
    int d = threadIdx.x;  // 128
    int n0 = blockIdx.x * 64;
    if (n0 >= n_nodes) return;
    int n1 = min(n0 + 64, n_nodes);
    int gcur = batch[n0];
    float acc = 0.0f;
    for (int n = n0; n < n1; ++n) {
        int g = batch[n];
        float v = h[(size_t)n * D_DIM + d];
        if (g != gcur) {
            unsafeAtomicAdd(&gsum[gcur * D_DIM + d], acc);
            acc = 0.0f;
            gcur = g;
        }
        acc += v;
    }
    unsafeAtomicAdd(&gsum[gcur * D_DIM + d], acc);
}

__global__ void cls_kernel(const float* __restrict__ gsum,
                           const float* __restrict__ gcnt,
                           const float* __restrict__ Wcls,
                           const float* __restrict__ bcls,
                           float* __restrict__ out) {
    int id = blockIdx.x * blockDim.x + threadIdx.x;
    if (id >= 128 * 16) return;
    int g = id >> 4, c = id & 15;
    float rc = 1.0f / fmaxf(gcnt[g], 1.0f);
    float acc = 0.0f;
    for (int d = 0; d < D_DIM; ++d)
        acc = fmaf(gsum[g * D_DIM + d], Wcls[d * 16 + c], acc);
    out[id] = acc * rc + bcls[c];
}

extern "C" void kernel_launch(void* const* d_in, const int* in_sizes, int n_in,
                              void* d_out, int out_size, void* d_ws, size_t ws_size,
                              hipStream_t stream) {
    const float* x      = (const float*)d_in[0];
    const int*   ei     = (const int*)d_in[1];
    const int*   etype  = (const int*)d_in[2];
    const int*   batch  = (const int*)d_in[3];
    const float* Wrel1  = (const float*)d_in[4];
    const float* Wroot1 = (const float*)d_in[5];
    const float* b1     = (const float*)d_in[6];
    const float* Wrel2  = (const float*)d_in[7];
    const float* Wroot2 = (const float*)d_in[8];
    const float* b2     = (const float*)d_in[9];
    const float* Wcls   = (const float*)d_in[10];
    const float* bcls   = (const float*)d_in[11];
    float* out = (float*)d_out;

    const int N = in_sizes[0] / D_DIM;  // 50000
    const int E = in_sizes[1] / 2;      // 800000
    const int NSEG = N * N_REL;         // 200000
    const int* src = ei;
    const int* dst = ei + E;

    // workspace layout
    float* h1    = (float*)d_ws;                   // N*128
    float* h2    = h1 + (size_t)N * D_DIM;         // N*128
    float* gsum  = h2 + (size_t)N * D_DIM;         // 128*128
    float* gcnt  = gsum + 128 * D_DIM;             // 128
    int* icnt    = (int*)(gcnt + 128);             // NSEG
    int* offsets = icnt + NSEG;                    // NSEG+1
    int* wpos    = offsets + NSEG + 1;             // NSEG
    int* bsum    = wpos + NSEG;                    // 1024
    int* esorted = bsum + 1024;                    // E
    uintptr_t p = (uintptr_t)(esorted + E);
    p = (p + 15) & ~(uintptr_t)15;
    ushort* Wpk1 = (ushort*)p;                     // 5*32*64*8 = 81920 ushorts
    ushort* Wpk2 = Wpk1 + 81920;

    const int nb = cdiv(NSEG, 256);  // 782 (<=1024)

    hipMemsetAsync(icnt, 0, (size_t)NSEG * sizeof(int), stream);
    hipMemsetAsync(gsum, 0, 128 * D_DIM * sizeof(float), stream);

    // ---- CSR build over seg = dst*4 + rel ----
    count_edges_kernel<<<cdiv(E, 256), 256, 0, stream>>>(dst, etype, icnt, E);
    scan_block_sums<<<nb, 256, 0, stream>>>(icnt, bsum, NSEG);
    scan_partials<<<1, 1024, 0, stream>>>(bsum, nb);
    scan_final<<<nb, 256, 0, stream>>>(icnt, bsum, offsets, wpos, NSEG);
    place_edges_kernel<<<cdiv(E, 256), 256, 0, stream>>>(src, dst, etype, wpos,
                                                         esorted, E);
    graph_bounds_kernel<<<1, 128, 0, stream>>>(batch, N, gcnt);

    // ---- pack weights into MFMA B-fragment layout (bf16) ----
    pack_w_kernel<<<dim3(8, 5), 256, 0, stream>>>(Wrel1, Wroot1, Wpk1);
    pack_w_kernel<<<dim3(8, 5), 256, 0, stream>>>(Wrel2, Wroot2, Wpk2);

    // ---- fused layers ----
    rgcn_fused_kernel<<<cdiv(N, 64), 256, 0, stream>>>(
        x, offsets, esorted, Wpk1, b1, h1, N);
    rgcn_fused_kernel<<<cdiv(N, 64), 256, 0, stream>>>(
        h1, offsets, esorted, Wpk2, b2, h2, N);

    // ---- global mean pool + classifier ----
    pool_kernel<<<cdiv(N, 64), 128, 0, stream>>>(h2, batch, gsum, N);
    cls_kernel<<<8, 256, 0, stream>>>(gsum, gcnt, Wcls, bcls, out);
}

// Round 4
// 388.843 us; speedup vs baseline: 8.1902x; 1.1176x over previous
//
#include <hip/hip_runtime.h>

#define D_DIM 128
#define N_REL 4

typedef __attribute__((ext_vector_type(8))) short bf16x8;
typedef __attribute__((ext_vector_type(4))) float f32x4;

static inline int cdiv(int a, int b) { return (a + b - 1) / b; }

__device__ inline ushort f2bf(float f) {
    union { float f; unsigned u; } v;
    v.f = f;
    unsigned r = v.u + 0x7FFFu + ((v.u >> 16) & 1u);  // RNE
    return (ushort)(r >> 16);
}

__device__ inline float bf2f(ushort u) {
    union { unsigned u; float f; } v;
    v.u = (unsigned)u << 16;
    return v.f;
}

// ---------------------------------------------------------------------------
// fp32 -> bf16 cast (vectorized: float4 -> ushort4)
// ---------------------------------------------------------------------------
__global__ void cast_bf16_kernel(const float* __restrict__ x,
                                 ushort* __restrict__ xb, int n4) {
    int i = blockIdx.x * blockDim.x + threadIdx.x;
    if (i < n4) {
        float4 v = ((const float4*)x)[i];
        ushort4 o;
        o.x = f2bf(v.x); o.y = f2bf(v.y); o.z = f2bf(v.z); o.w = f2bf(v.w);
        ((ushort4*)xb)[i] = o;
    }
}

// ---------------------------------------------------------------------------
// icnt[dst*4+rel]++ per edge
// ---------------------------------------------------------------------------
__global__ void count_edges_kernel(const int* __restrict__ dst,
                                   const int* __restrict__ et,
                                   int* __restrict__ icnt, int nEdges) {
    int e = blockIdx.x * blockDim.x + threadIdx.x;
    if (e < nEdges) atomicAdd(&icnt[dst[e] * N_REL + et[e]], 1);
}

// ---------------------------------------------------------------------------
// 3-kernel exclusive scan over nseg=200000 ints
// ---------------------------------------------------------------------------
__global__ void scan_block_sums(const int* __restrict__ icnt,
                                int* __restrict__ bsum, int nseg) {
    __shared__ int s[256];
    int t = threadIdx.x;
    int i = blockIdx.x * 256 + t;
    s[t] = (i < nseg) ? icnt[i] : 0;
    __syncthreads();
    for (int off = 128; off > 0; off >>= 1) {
        if (t < off) s[t] += s[t + off];
        __syncthreads();
    }
    if (t == 0) bsum[blockIdx.x] = s[0];
}

__global__ void scan_partials(int* __restrict__ bsum, int nb) {
    __shared__ int s[1024];
    int t = threadIdx.x;
    int v = (t < nb) ? bsum[t] : 0;
    s[t] = v;
    __syncthreads();
    for (int off = 1; off < 1024; off <<= 1) {
        int u = (t >= off) ? s[t - off] : 0;
        __syncthreads();
        s[t] += u;
        __syncthreads();
    }
    if (t < nb) bsum[t] = s[t] - v;  // exclusive prefix of block sums
}

__global__ void scan_final(const int* __restrict__ icnt,
                           const int* __restrict__ bsum,
                           int* __restrict__ offsets, int* __restrict__ wpos,
                           int nseg) {
    __shared__ int s[256];
    int t = threadIdx.x;
    int i = blockIdx.x * 256 + t;
    int v = (i < nseg) ? icnt[i] : 0;
    s[t] = v;
    __syncthreads();
    for (int off = 1; off < 256; off <<= 1) {
        int u = (t >= off) ? s[t - off] : 0;
        __syncthreads();
        s[t] += u;
        __syncthreads();
    }
    int excl = s[t] - v + bsum[blockIdx.x];
    if (i < nseg) {
        offsets[i] = excl;
        wpos[i] = excl;
        if (i == nseg - 1) offsets[nseg] = excl + v;
    }
}

__global__ void place_edges_kernel(const int* __restrict__ src,
                                   const int* __restrict__ dst,
                                   const int* __restrict__ et,
                                   int* __restrict__ wpos,
                                   int* __restrict__ esorted, int nEdges) {
    int e = blockIdx.x * blockDim.x + threadIdx.x;
    if (e < nEdges) {
        int seg = dst[e] * N_REL + et[e];
        int pos = atomicAdd(&wpos[seg], 1);
        esorted[pos] = src[e];
    }
}

// ---------------------------------------------------------------------------
// Pack both layers' weights [Wrel(4) | Wroot] into bf16 MFMA B-fragment
// layout for 16x16x32: lane holds B[k=kt*32+(lane>>4)*8+j][n=nt*16+(lane&15)]
// out[((mat*32 + kt*8 + nt)*64 + lane)*8 + j].  grid (8, 5 mats, 2 layers).
// ---------------------------------------------------------------------------
__global__ void pack_w_kernel(const float* __restrict__ Wrel1,
                              const float* __restrict__ Wroot1,
                              const float* __restrict__ Wrel2,
                              const float* __restrict__ Wroot2,
                              ushort* __restrict__ out1,
                              ushort* __restrict__ out2) {
    int mat = blockIdx.y;
    const float* Wrel = blockIdx.z ? Wrel2 : Wrel1;
    const float* Wroot = blockIdx.z ? Wroot2 : Wroot1;
    ushort* out = blockIdx.z ? out2 : out1;
    const float* W = (mat < N_REL) ? (Wrel + (size_t)mat * D_DIM * D_DIM) : Wroot;
    int t = blockIdx.x * 256 + threadIdx.x;  // 0..2047 within mat
    int lane = t & 63;
    int tile = t >> 6;  // 0..31 = kt*8+nt
    int kt = tile >> 3;
    int nt = tile & 7;
    int n = nt * 16 + (lane & 15);
    int kb = kt * 32 + (lane >> 4) * 8;
    ushort* o = out + (((size_t)mat * 32 + tile) * 64 + lane) * 8;
    ushort4 lo, hi;
    lo.x = f2bf(W[(kb + 0) * D_DIM + n]);
    lo.y = f2bf(W[(kb + 1) * D_DIM + n]);
    lo.z = f2bf(W[(kb + 2) * D_DIM + n]);
    lo.w = f2bf(W[(kb + 3) * D_DIM + n]);
    hi.x = f2bf(W[(kb + 4) * D_DIM + n]);
    hi.y = f2bf(W[(kb + 5) * D_DIM + n]);
    hi.z = f2bf(W[(kb + 6) * D_DIM + n]);
    hi.w = f2bf(W[(kb + 7) * D_DIM + n]);
    *(ushort4*)(o) = lo;
    *(ushort4*)(o + 4) = hi;
}

// ---------------------------------------------------------------------------
// Gather/mean kernel: one half-wave (32 lanes) per segment seg = n*4+rel.
// Lane hl covers bf16 elems [hl*4, hl*4+4). M[seg,:] = mean of Xb[src] rows.
// 100k waves -> full occupancy for latency hiding (vs 3125 when fused).
// ---------------------------------------------------------------------------
__global__ __launch_bounds__(256) void gather_kernel(
    const ushort* __restrict__ Xb, const int* __restrict__ offsets,
    const int* __restrict__ esorted, ushort* __restrict__ M, int nseg) {
    int gid = blockIdx.x * blockDim.x + threadIdx.x;
    int seg = gid >> 5;
    int hl = gid & 31;
    if (seg >= nseg) return;
    int beg = offsets[seg];
    int end = offsets[seg + 1];
    const ushort* xb = Xb + hl * 4;
    float4 v0 = make_float4(0.f, 0.f, 0.f, 0.f);
    float4 v1 = v0, v2 = v0, v3 = v0;
    int e = beg;
    for (; e + 4 <= end; e += 4) {
        int s0 = esorted[e + 0];
        int s1 = esorted[e + 1];
        int s2 = esorted[e + 2];
        int s3 = esorted[e + 3];
        ushort4 a0 = *(const ushort4*)(xb + (size_t)s0 * D_DIM);
        ushort4 a1 = *(const ushort4*)(xb + (size_t)s1 * D_DIM);
        ushort4 a2 = *(const ushort4*)(xb + (size_t)s2 * D_DIM);
        ushort4 a3 = *(const ushort4*)(xb + (size_t)s3 * D_DIM);
        v0.x += bf2f(a0.x); v0.y += bf2f(a0.y); v0.z += bf2f(a0.z); v0.w += bf2f(a0.w);
        v1.x += bf2f(a1.x); v1.y += bf2f(a1.y); v1.z += bf2f(a1.z); v1.w += bf2f(a1.w);
        v2.x += bf2f(a2.x); v2.y += bf2f(a2.y); v2.z += bf2f(a2.z); v2.w += bf2f(a2.w);
        v3.x += bf2f(a3.x); v3.y += bf2f(a3.y); v3.z += bf2f(a3.z); v3.w += bf2f(a3.w);
    }
    for (; e < end; ++e) {
        int s0 = esorted[e];
        ushort4 a0 = *(const ushort4*)(xb + (size_t)s0 * D_DIM);
        v0.x += bf2f(a0.x); v0.y += bf2f(a0.y); v0.z += bf2f(a0.z); v0.w += bf2f(a0.w);
    }
    float sc = 1.0f / fmaxf((float)(end - beg), 1.0f);
    float4 v;
    v.x = (v0.x + v1.x + v2.x + v3.x) * sc;
    v.y = (v0.y + v1.y + v2.y + v3.y) * sc;
    v.z = (v0.z + v1.z + v2.z + v3.z) * sc;
    v.w = (v0.w + v1.w + v2.w + v3.w) * sc;
    ushort4 o;
    o.x = f2bf(v.x); o.y = f2bf(v.y); o.z = f2bf(v.z); o.w = f2bf(v.w);
    *(ushort4*)(M + (size_t)seg * D_DIM + hl * 4) = o;
}

// ---------------------------------------------------------------------------
// Transform GEMM: out[n,f] = relu( [M(n,0..3) | Xb(n)] @ [Wrel|Wroot] + bias )
// No LDS: A-fragments are direct 16B global loads (bf16 rows ARE the MFMA
// A-layout: lane holds A[m=lane&15][k=(lane>>4)*8+j]); B from packed Wpk.
// Wave = 16 rows x 128 cols; 5 phases x 4 k-tiles x 8 n-tiles = 160 MFMA.
// ---------------------------------------------------------------------------
__global__ __launch_bounds__(256) void gemm_kernel(
    const ushort* __restrict__ M, const ushort* __restrict__ Xb,
    const ushort* __restrict__ Wpk, const float* __restrict__ bias,
    ushort* __restrict__ outb, int n_nodes) {
    const int tid = threadIdx.x;
    const int wave = tid >> 6;
    const int lane = tid & 63;
    const int m = lane & 15;
    const int q = lane >> 4;
    const int r0 = blockIdx.x * 64 + wave * 16;
    const int n = min(r0 + m, n_nodes - 1);  // clamp; stores are guarded

    const ushort* aM = M + (size_t)n * (N_REL * D_DIM) + q * 8;
    const ushort* aX = Xb + (size_t)n * D_DIM + q * 8;
    const ushort* Wl = Wpk + (size_t)lane * 8;

    f32x4 acc[8];
#pragma unroll
    for (int nt = 0; nt < 8; ++nt) acc[nt] = (f32x4){0.f, 0.f, 0.f, 0.f};

#pragma unroll
    for (int phase = 0; phase < 5; ++phase) {
        const ushort* abase = (phase < N_REL) ? (aM + phase * D_DIM) : aX;
        const ushort* Wp = Wl + (size_t)phase * 32 * 64 * 8;
#pragma unroll
        for (int kt = 0; kt < 4; ++kt) {
            bf16x8 a = *(const bf16x8*)(abase + kt * 32);
#pragma unroll
            for (int nt = 0; nt < 8; ++nt) {
                bf16x8 b = *(const bf16x8*)(Wp + ((size_t)(kt * 8 + nt) * 64) * 8);
                acc[nt] = __builtin_amdgcn_mfma_f32_16x16x32_bf16(a, b, acc[nt], 0, 0, 0);
            }
        }
    }

    // epilogue: C/D layout col=lane&15, row=q*4+r
#pragma unroll
    for (int nt = 0; nt < 8; ++nt) {
        int col = nt * 16 + m;
        float bv = bias[col];
#pragma unroll
        for (int r = 0; r < 4; ++r) {
            int row = r0 + q * 4 + r;
            if (row < n_nodes)
                outb[(size_t)row * D_DIM + col] = f2bf(fmaxf(acc[nt][r] + bv, 0.0f));
        }
    }
}

// ---------------------------------------------------------------------------
// Fused global mean pool + classifier. Block g (of 128): nodes [lb(g),lb(g+1))
// (batch sorted). Thread d sums column d (coalesced 256B rows), mean to LDS,
// then 16 threads compute the 16 class outputs.
// ---------------------------------------------------------------------------
__global__ __launch_bounds__(128) void poolcls_kernel(
    const ushort* __restrict__ hb, const int* __restrict__ batch,
    const float* __restrict__ Wcls, const float* __restrict__ bcls,
    float* __restrict__ out, int n_nodes) {
    __shared__ float mean[D_DIM];
    int g = blockIdx.x;
    int d = threadIdx.x;
    auto lb = [&](int val) {
        int lo = 0, hi = n_nodes;
        while (lo < hi) {
            int mid = (lo + hi) >> 1;
            if (batch[mid] < val) lo = mid + 1; else hi = mid;
        }
        return lo;
    };
    int lo = lb(g), hi = lb(g + 1);
    float a0 = 0.f, a1 = 0.f, a2 = 0.f, a3 = 0.f;
    int nn = lo;
    for (; nn + 4 <= hi; nn += 4) {
        a0 += bf2f(hb[(size_t)(nn + 0) * D_DIM + d]);
        a1 += bf2f(hb[(size_t)(nn + 1) * D_DIM + d]);
        a2 += bf2f(hb[(size_t)(nn + 2) * D_DIM + d]);
        a3 += bf2f(hb[(size_t)(nn + 3) * D_DIM + d]);
    }
    for (; nn < hi; ++nn) a0 += bf2f(hb[(size_t)nn * D_DIM + d]);
    mean[d] = (a0 + a1 + a2 + a3) / fmaxf((float)(hi - lo), 1.0f);
    __syncthreads();
    if (d < 16) {
        float acc = bcls[d];
        for (int k = 0; k < D_DIM; ++k)
            acc = fmaf(mean[k], Wcls[k * 16 + d], acc);
        out[g * 16 + d] = acc;
    }
}

extern "C" void kernel_launch(void* const* d_in, const int* in_sizes, int n_in,
                              void* d_out, int out_size, void* d_ws, size_t ws_size,
                              hipStream_t stream) {
    const float* x      = (const float*)d_in[0];
    const int*   ei     = (const int*)d_in[1];
    const int*   etype  = (const int*)d_in[2];
    const int*   batch  = (const int*)d_in[3];
    const float* Wrel1  = (const float*)d_in[4];
    const float* Wroot1 = (const float*)d_in[5];
    const float* b1     = (const float*)d_in[6];
    const float* Wrel2  = (const float*)d_in[7];
    const float* Wroot2 = (const float*)d_in[8];
    const float* b2     = (const float*)d_in[9];
    const float* Wcls   = (const float*)d_in[10];
    const float* bcls   = (const float*)d_in[11];
    float* out = (float*)d_out;

    const int N = in_sizes[0] / D_DIM;  // 50000
    const int E = in_sizes[1] / 2;      // 800000
    const int NSEG = N * N_REL;         // 200000
    const int* src = ei;
    const int* dst = ei + E;

    // workspace layout (all bf16 chunks are 16B-multiple sizes)
    ushort* Xb   = (ushort*)d_ws;                  // N*128
    ushort* h1b  = Xb + (size_t)N * D_DIM;         // N*128
    ushort* h2b  = h1b + (size_t)N * D_DIM;        // N*128
    ushort* M    = h2b + (size_t)N * D_DIM;        // N*512 (mean per (n,rel))
    ushort* Wpk1 = M + (size_t)N * N_REL * D_DIM;  // 81920
    ushort* Wpk2 = Wpk1 + 81920;                   // 81920
    int* icnt    = (int*)(Wpk2 + 81920);           // NSEG
    int* offsets = icnt + NSEG;                    // NSEG+1
    int* wpos    = offsets + NSEG + 1;             // NSEG
    int* bsum    = wpos + NSEG;                    // 1024
    int* esorted = bsum + 1024;                    // E

    const int nb = cdiv(NSEG, 256);  // 782 (<=1024)

    hipMemsetAsync(icnt, 0, (size_t)NSEG * sizeof(int), stream);

    // ---- CSR build over seg = dst*4 + rel, x cast, weight pack ----
    cast_bf16_kernel<<<cdiv(N * D_DIM / 4, 256), 256, 0, stream>>>(
        x, Xb, N * D_DIM / 4);
    count_edges_kernel<<<cdiv(E, 256), 256, 0, stream>>>(dst, etype, icnt, E);
    scan_block_sums<<<nb, 256, 0, stream>>>(icnt, bsum, NSEG);
    scan_partials<<<1, 1024, 0, stream>>>(bsum, nb);
    scan_final<<<nb, 256, 0, stream>>>(icnt, bsum, offsets, wpos, NSEG);
    place_edges_kernel<<<cdiv(E, 256), 256, 0, stream>>>(src, dst, etype, wpos,
                                                         esorted, E);
    pack_w_kernel<<<dim3(8, 5, 2), 256, 0, stream>>>(Wrel1, Wroot1, Wrel2,
                                                     Wroot2, Wpk1, Wpk2);

    // ---- layer 1 ----
    gather_kernel<<<cdiv(NSEG * 32, 256), 256, 0, stream>>>(
        Xb, offsets, esorted, M, NSEG);
    gemm_kernel<<<cdiv(N, 64), 256, 0, stream>>>(M, Xb, Wpk1, b1, h1b, N);

    // ---- layer 2 ----
    gather_kernel<<<cdiv(NSEG * 32, 256), 256, 0, stream>>>(
        h1b, offsets, esorted, M, NSEG);
    gemm_kernel<<<cdiv(N, 64), 256, 0, stream>>>(M, h1b, Wpk2, b2, h2b, N);

    // ---- global mean pool + classifier ----
    poolcls_kernel<<<128, 128, 0, stream>>>(h2b, batch, Wcls, bcls, out, N);
}

// Round 6
// 338.566 us; speedup vs baseline: 9.4064x; 1.1485x over previous
//
#include <hip/hip_runtime.h>

#define D_DIM 128
#define N_REL 4

typedef __attribute__((ext_vector_type(8))) short bf16x8;
typedef __attribute__((ext_vector_type(4))) float f32x4;

static inline int cdiv(int a, int b) { return (a + b - 1) / b; }

__device__ inline ushort f2bf(float f) {
    union { float f; unsigned u; } v;
    v.f = f;
    unsigned r = v.u + 0x7FFFu + ((v.u >> 16) & 1u);  // RNE
    return (ushort)(r >> 16);
}

__device__ inline float bf2f(ushort u) {
    union { unsigned u; float f; } v;
    v.u = (unsigned)u << 16;
    return v.f;
}

__device__ inline float uif(unsigned u) {
    union { unsigned u; float f; } v;
    v.u = u;
    return v.f;
}

// ---------------------------------------------------------------------------
// Fused prep kernel, branch by blockIdx range:
//   [0, 6250)         : cast x fp32 -> bf16 (float4 -> ushort4)
//   [6250, 9375)      : count edges into 8 copy-major replicas + capture rank
//   [9375, 9455)      : pack both layers' weights to MFMA B-frag layout
// Count copy index = edge_block & 7 (place_edges recomputes identically).
// Rank order is schedule-dependent, but gather's fp64-exact sums make the
// result independent of within-segment edge order (bitwise deterministic).
// ---------------------------------------------------------------------------
#define CAST_B 6250
#define CNT_B 3125
#define PACK_B 80

__global__ __launch_bounds__(256) void prep_kernel(
    const float* __restrict__ x, ushort* __restrict__ Xb,
    const int* __restrict__ dst, const int* __restrict__ et,
    int* __restrict__ icnt8, int* __restrict__ rankbuf,
    const float* __restrict__ Wrel1, const float* __restrict__ Wroot1,
    const float* __restrict__ Wrel2, const float* __restrict__ Wroot2,
    ushort* __restrict__ Wpk1, ushort* __restrict__ Wpk2,
    int n4, int nEdges, int nseg) {
    int b = blockIdx.x;
    if (b < CAST_B) {
        int i = b * 256 + threadIdx.x;
        if (i < n4) {
            float4 v = ((const float4*)x)[i];
            ushort4 o;
            o.x = f2bf(v.x); o.y = f2bf(v.y); o.z = f2bf(v.z); o.w = f2bf(v.w);
            ((ushort4*)Xb)[i] = o;
        }
    } else if (b < CAST_B + CNT_B) {
        int eb = b - CAST_B;
        int e = eb * 256 + threadIdx.x;
        if (e < nEdges) {
            int seg = dst[e] * N_REL + et[e];
            int copy = eb & 7;
            int r = atomicAdd(&icnt8[(size_t)copy * nseg + seg], 1);
            rankbuf[e] = r;
        }
    } else {
        int pb = b - (CAST_B + CNT_B);
        int layer = pb / 40;
        int rem = pb % 40;
        int mat = rem >> 3;
        int blk = rem & 7;
        const float* Wrel = layer ? Wrel2 : Wrel1;
        const float* Wroot = layer ? Wroot2 : Wroot1;
        ushort* out = layer ? Wpk2 : Wpk1;
        const float* W = (mat < N_REL) ? (Wrel + (size_t)mat * D_DIM * D_DIM) : Wroot;
        int t = blk * 256 + threadIdx.x;  // 0..2047 within mat
        int lane = t & 63;
        int tile = t >> 6;  // kt*8+nt
        int kt = tile >> 3;
        int nt = tile & 7;
        int n = nt * 16 + (lane & 15);
        int kb = kt * 32 + (lane >> 4) * 8;
        ushort* o = out + (((size_t)mat * 32 + tile) * 64 + lane) * 8;
        ushort4 lo, hi;
        lo.x = f2bf(W[(kb + 0) * D_DIM + n]);
        lo.y = f2bf(W[(kb + 1) * D_DIM + n]);
        lo.z = f2bf(W[(kb + 2) * D_DIM + n]);
        lo.w = f2bf(W[(kb + 3) * D_DIM + n]);
        hi.x = f2bf(W[(kb + 4) * D_DIM + n]);
        hi.y = f2bf(W[(kb + 5) * D_DIM + n]);
        hi.z = f2bf(W[(kb + 6) * D_DIM + n]);
        hi.w = f2bf(W[(kb + 7) * D_DIM + n]);
        *(ushort4*)(o) = lo;
        *(ushort4*)(o + 4) = hi;
    }
}

// ---------------------------------------------------------------------------
// Scan step 1: totseg[i] = sum of 8 copies; block-reduce -> bsum
// ---------------------------------------------------------------------------
__global__ void scan_block_sums(const int* __restrict__ icnt8,
                                int* __restrict__ totseg,
                                int* __restrict__ bsum, int nseg) {
    __shared__ int s[256];
    int t = threadIdx.x;
    int i = blockIdx.x * 256 + t;
    int tot = 0;
    if (i < nseg) {
#pragma unroll
        for (int c = 0; c < 8; ++c) tot += icnt8[(size_t)c * nseg + i];
        totseg[i] = tot;
    }
    s[t] = tot;
    __syncthreads();
    for (int off = 128; off > 0; off >>= 1) {
        if (t < off) s[t] += s[t + off];
        __syncthreads();
    }
    if (t == 0) bsum[blockIdx.x] = s[0];
}

__global__ void scan_partials(int* __restrict__ bsum, int nb) {
    __shared__ int s[1024];
    int t = threadIdx.x;
    int v = (t < nb) ? bsum[t] : 0;
    s[t] = v;
    __syncthreads();
    for (int off = 1; off < 1024; off <<= 1) {
        int u = (t >= off) ? s[t - off] : 0;
        __syncthreads();
        s[t] += u;
        __syncthreads();
    }
    if (t < nb) bsum[t] = s[t] - v;  // exclusive prefix of block sums
}

// ---------------------------------------------------------------------------
// Scan step 3: offsets[seg] (exclusive over totals) + per-copy bases
// pbase[c][seg] = offsets[seg] + sum_{c'<c} icnt8[c'][seg]
// ---------------------------------------------------------------------------
__global__ void scan_final(const int* __restrict__ icnt8,
                           const int* __restrict__ totseg,
                           const int* __restrict__ bsum,
                           int* __restrict__ offsets,
                           int* __restrict__ pbase, int nseg) {
    __shared__ int s[256];
    int t = threadIdx.x;
    int i = blockIdx.x * 256 + t;
    int v = (i < nseg) ? totseg[i] : 0;
    s[t] = v;
    __syncthreads();
    for (int off = 1; off < 256; off <<= 1) {
        int u = (t >= off) ? s[t - off] : 0;
        __syncthreads();
        s[t] += u;
        __syncthreads();
    }
    int excl = s[t] - v + bsum[blockIdx.x];
    if (i < nseg) {
        offsets[i] = excl;
        int run = excl;
#pragma unroll
        for (int c = 0; c < 8; ++c) {
            pbase[(size_t)c * nseg + i] = run;
            run += icnt8[(size_t)c * nseg + i];
        }
        if (i == nseg - 1) offsets[nseg] = run;
    }
}

// ---------------------------------------------------------------------------
// Atomic-free placement: pos = pbase[copy][seg] + rank[e]
// ---------------------------------------------------------------------------
__global__ __launch_bounds__(256) void place_edges_kernel(
    const int* __restrict__ src, const int* __restrict__ dst,
    const int* __restrict__ et, const int* __restrict__ rankbuf,
    const int* __restrict__ pbase, int* __restrict__ esorted,
    int nEdges, int nseg) {
    int e = blockIdx.x * blockDim.x + threadIdx.x;
    if (e < nEdges) {
        int seg = dst[e] * N_REL + et[e];
        int copy = (e >> 8) & 7;
        int pos = pbase[(size_t)copy * nseg + seg] + rankbuf[e];
        esorted[pos] = src[e];
    }
}

// ---------------------------------------------------------------------------
// Gather/mean: one quarter-wave (16 lanes x 16B) per segment.
// Lane ql covers bf16 elems [ql*8, ql*8+8). M[seg,:] = mean of Xb[src] rows.
// fp64 accumulation: sums of bf16 values (8-bit significands) are EXACT in
// fp64 for realistic exponent spreads -> result is independent of the
// (schedule-dependent) edge order within a segment -> bitwise-deterministic
// output on every call (required by the harness's post-timing revalidation).
// ---------------------------------------------------------------------------
__global__ __launch_bounds__(256) void gather_kernel(
    const ushort* __restrict__ Xb, const int* __restrict__ offsets,
    const int* __restrict__ esorted, ushort* __restrict__ M, int nseg) {
    int gid = blockIdx.x * blockDim.x + threadIdx.x;
    int seg = gid >> 4;
    int ql = gid & 15;
    if (seg >= nseg) return;
    int beg = offsets[seg];
    int end = offsets[seg + 1];
    const ushort* xb = Xb + ql * 8;
    double a[8], b[8];
#pragma unroll
    for (int j = 0; j < 8; ++j) { a[j] = 0.0; b[j] = 0.0; }
    int e = beg;
    for (; e + 2 <= end; e += 2) {
        int s0 = esorted[e];
        int s1 = esorted[e + 1];
        uint4 u0 = *(const uint4*)(xb + (size_t)s0 * D_DIM);
        uint4 u1 = *(const uint4*)(xb + (size_t)s1 * D_DIM);
        a[0] += (double)uif(u0.x << 16); a[1] += (double)uif(u0.x & 0xFFFF0000u);
        a[2] += (double)uif(u0.y << 16); a[3] += (double)uif(u0.y & 0xFFFF0000u);
        a[4] += (double)uif(u0.z << 16); a[5] += (double)uif(u0.z & 0xFFFF0000u);
        a[6] += (double)uif(u0.w << 16); a[7] += (double)uif(u0.w & 0xFFFF0000u);
        b[0] += (double)uif(u1.x << 16); b[1] += (double)uif(u1.x & 0xFFFF0000u);
        b[2] += (double)uif(u1.y << 16); b[3] += (double)uif(u1.y & 0xFFFF0000u);
        b[4] += (double)uif(u1.z << 16); b[5] += (double)uif(u1.z & 0xFFFF0000u);
        b[6] += (double)uif(u1.w << 16); b[7] += (double)uif(u1.w & 0xFFFF0000u);
    }
    if (e < end) {
        int s0 = esorted[e];
        uint4 u0 = *(const uint4*)(xb + (size_t)s0 * D_DIM);
        a[0] += (double)uif(u0.x << 16); a[1] += (double)uif(u0.x & 0xFFFF0000u);
        a[2] += (double)uif(u0.y << 16); a[3] += (double)uif(u0.y & 0xFFFF0000u);
        a[4] += (double)uif(u0.z << 16); a[5] += (double)uif(u0.z & 0xFFFF0000u);
        a[6] += (double)uif(u0.w << 16); a[7] += (double)uif(u0.w & 0xFFFF0000u);
    }
    double sc = 1.0 / fmax((double)(end - beg), 1.0);
    float m0 = (float)((a[0] + b[0]) * sc);
    float m1 = (float)((a[1] + b[1]) * sc);
    float m2 = (float)((a[2] + b[2]) * sc);
    float m3 = (float)((a[3] + b[3]) * sc);
    float m4 = (float)((a[4] + b[4]) * sc);
    float m5 = (float)((a[5] + b[5]) * sc);
    float m6 = (float)((a[6] + b[6]) * sc);
    float m7 = (float)((a[7] + b[7]) * sc);
    uint4 o;
    o.x = (unsigned)f2bf(m0) | ((unsigned)f2bf(m1) << 16);
    o.y = (unsigned)f2bf(m2) | ((unsigned)f2bf(m3) << 16);
    o.z = (unsigned)f2bf(m4) | ((unsigned)f2bf(m5) << 16);
    o.w = (unsigned)f2bf(m6) | ((unsigned)f2bf(m7) << 16);
    *(uint4*)(M + (size_t)seg * D_DIM + ql * 8) = o;
}

// ---------------------------------------------------------------------------
// Transform GEMM, 32 rows/wave (2 m-tiles share each B-fragment load).
// Block = 4 waves = 128 rows x 128 cols. A = [M(n,0..3) | Xb(n)], K=640.
// Direct global A/B fragment loads (bf16 rows ARE the MFMA A-layout).
// ---------------------------------------------------------------------------
__global__ __launch_bounds__(256) void gemm_kernel(
    const ushort* __restrict__ M, const ushort* __restrict__ Xb,
    const ushort* __restrict__ Wpk, const float* __restrict__ bias,
    ushort* __restrict__ outb, int n_nodes) {
    const int tid = threadIdx.x;
    const int wave = tid >> 6;
    const int lane = tid & 63;
    const int m = lane & 15;
    const int q = lane >> 4;
    const int r0 = blockIdx.x * 128 + wave * 32;
    const int n0 = min(r0 + m, n_nodes - 1);       // clamp; stores guarded
    const int n1 = min(r0 + 16 + m, n_nodes - 1);

    const ushort* aM0 = M + (size_t)n0 * (N_REL * D_DIM) + q * 8;
    const ushort* aM1 = M + (size_t)n1 * (N_REL * D_DIM) + q * 8;
    const ushort* aX0 = Xb + (size_t)n0 * D_DIM + q * 8;
    const ushort* aX1 = Xb + (size_t)n1 * D_DIM + q * 8;
    const ushort* Wl = Wpk + (size_t)lane * 8;

    f32x4 acc[2][8];
#pragma unroll
    for (int t = 0; t < 2; ++t)
#pragma unroll
        for (int nt = 0; nt < 8; ++nt) acc[t][nt] = (f32x4){0.f, 0.f, 0.f, 0.f};

#pragma unroll
    for (int phase = 0; phase < 5; ++phase) {
        const ushort* ab0 = (phase < N_REL) ? (aM0 + phase * D_DIM) : aX0;
        const ushort* ab1 = (phase < N_REL) ? (aM1 + phase * D_DIM) : aX1;
        const ushort* Wp = Wl + (size_t)phase * 32 * 64 * 8;
#pragma unroll
        for (int kt = 0; kt < 4; ++kt) {
            bf16x8 a0 = *(const bf16x8*)(ab0 + kt * 32);
            bf16x8 a1 = *(const bf16x8*)(ab1 + kt * 32);
#pragma unroll
            for (int nt = 0; nt < 8; ++nt) {
                bf16x8 b = *(const bf16x8*)(Wp + ((size_t)(kt * 8 + nt) * 64) * 8);
                acc[0][nt] = __builtin_amdgcn_mfma_f32_16x16x32_bf16(a0, b, acc[0][nt], 0, 0, 0);
                acc[1][nt] = __builtin_amdgcn_mfma_f32_16x16x32_bf16(a1, b, acc[1][nt], 0, 0, 0);
            }
        }
    }

    // epilogue: C/D layout col=lane&15, row=q*4+r (per m-tile t: +t*16)
#pragma unroll
    for (int t = 0; t < 2; ++t) {
#pragma unroll
        for (int nt = 0; nt < 8; ++nt) {
            int col = nt * 16 + m;
            float bv = bias[col];
#pragma unroll
            for (int r = 0; r < 4; ++r) {
                int row = r0 + t * 16 + q * 4 + r;
                if (row < n_nodes)
                    outb[(size_t)row * D_DIM + col] = f2bf(fmaxf(acc[t][nt][r] + bv, 0.0f));
            }
        }
    }
}

// ---------------------------------------------------------------------------
// Fused global mean pool + classifier (batch sorted -> binary search bounds).
// Sequential fixed-order fp32 sums: deterministic across calls.
// ---------------------------------------------------------------------------
__global__ __launch_bounds__(128) void poolcls_kernel(
    const ushort* __restrict__ hb, const int* __restrict__ batch,
    const float* __restrict__ Wcls, const float* __restrict__ bcls,
    float* __restrict__ out, int n_nodes) {
    __shared__ float mean[D_DIM];
    int g = blockIdx.x;
    int d = threadIdx.x;
    auto lb = [&](int val) {
        int lo = 0, hi = n_nodes;
        while (lo < hi) {
            int mid = (lo + hi) >> 1;
            if (batch[mid] < val) lo = mid + 1; else hi = mid;
        }
        return lo;
    };
    int lo = lb(g), hi = lb(g + 1);
    float a0 = 0.f, a1 = 0.f, a2 = 0.f, a3 = 0.f;
    int nn = lo;
    for (; nn + 4 <= hi; nn += 4) {
        a0 += bf2f(hb[(size_t)(nn + 0) * D_DIM + d]);
        a1 += bf2f(hb[(size_t)(nn + 1) * D_DIM + d]);
        a2 += bf2f(hb[(size_t)(nn + 2) * D_DIM + d]);
        a3 += bf2f(hb[(size_t)(nn + 3) * D_DIM + d]);
    }
    for (; nn < hi; ++nn) a0 += bf2f(hb[(size_t)nn * D_DIM + d]);
    mean[d] = (a0 + a1 + a2 + a3) / fmaxf((float)(hi - lo), 1.0f);
    __syncthreads();
    if (d < 16) {
        float acc = bcls[d];
        for (int k = 0; k < D_DIM; ++k)
            acc = fmaf(mean[k], Wcls[k * 16 + d], acc);
        out[g * 16 + d] = acc;
    }
}

extern "C" void kernel_launch(void* const* d_in, const int* in_sizes, int n_in,
                              void* d_out, int out_size, void* d_ws, size_t ws_size,
                              hipStream_t stream) {
    const float* x      = (const float*)d_in[0];
    const int*   ei     = (const int*)d_in[1];
    const int*   etype  = (const int*)d_in[2];
    const int*   batch  = (const int*)d_in[3];
    const float* Wrel1  = (const float*)d_in[4];
    const float* Wroot1 = (const float*)d_in[5];
    const float* b1     = (const float*)d_in[6];
    const float* Wrel2  = (const float*)d_in[7];
    const float* Wroot2 = (const float*)d_in[8];
    const float* b2     = (const float*)d_in[9];
    const float* Wcls   = (const float*)d_in[10];
    const float* bcls   = (const float*)d_in[11];
    float* out = (float*)d_out;

    const int N = in_sizes[0] / D_DIM;  // 50000
    const int E = in_sizes[1] / 2;      // 800000
    const int NSEG = N * N_REL;         // 200000
    const int* src = ei;
    const int* dst = ei + E;

    // workspace layout
    ushort* Xb   = (ushort*)d_ws;                  // N*128
    ushort* h1b  = Xb + (size_t)N * D_DIM;         // N*128
    ushort* h2b  = h1b + (size_t)N * D_DIM;        // N*128
    ushort* M    = h2b + (size_t)N * D_DIM;        // N*512
    ushort* Wpk1 = M + (size_t)N * N_REL * D_DIM;  // 81920
    ushort* Wpk2 = Wpk1 + 81920;                   // 81920
    int* icnt8   = (int*)(Wpk2 + 81920);           // 8*NSEG
    int* totseg  = icnt8 + (size_t)8 * NSEG;       // NSEG
    int* offsets = totseg + NSEG;                  // NSEG+1
    int* pbase   = offsets + NSEG + 1;             // 8*NSEG
    int* bsum    = pbase + (size_t)8 * NSEG;       // 1024
    int* rankbuf = bsum + 1024;                    // E
    int* esorted = rankbuf + E;                    // E

    const int nb = cdiv(NSEG, 256);  // 782 (<=1024)

    hipMemsetAsync(icnt8, 0, (size_t)8 * NSEG * sizeof(int), stream);

    // ---- prep: cast + count(8-copy, rank capture) + pack ----
    prep_kernel<<<CAST_B + CNT_B + PACK_B, 256, 0, stream>>>(
        x, Xb, dst, etype, icnt8, rankbuf, Wrel1, Wroot1, Wrel2, Wroot2,
        Wpk1, Wpk2, N * D_DIM / 4, E, NSEG);

    // ---- scan + atomic-free placement ----
    scan_block_sums<<<nb, 256, 0, stream>>>(icnt8, totseg, bsum, NSEG);
    scan_partials<<<1, 1024, 0, stream>>>(bsum, nb);
    scan_final<<<nb, 256, 0, stream>>>(icnt8, totseg, bsum, offsets, pbase, NSEG);
    place_edges_kernel<<<cdiv(E, 256), 256, 0, stream>>>(
        src, dst, etype, rankbuf, pbase, esorted, E, NSEG);

    // ---- layer 1 ----
    gather_kernel<<<cdiv(NSEG * 16, 256), 256, 0, stream>>>(
        Xb, offsets, esorted, M, NSEG);
    gemm_kernel<<<cdiv(N, 128), 256, 0, stream>>>(M, Xb, Wpk1, b1, h1b, N);

    // ---- layer 2 ----
    gather_kernel<<<cdiv(NSEG * 16, 256), 256, 0, stream>>>(
        h1b, offsets, esorted, M, NSEG);
    gemm_kernel<<<cdiv(N, 128), 256, 0, stream>>>(M, h1b, Wpk2, b2, h2b, N);

    // ---- global mean pool + classifier ----
    poolcls_kernel<<<128, 128, 0, stream>>>(h2b, batch, Wcls, bcls, out, N);
}